// Round 7
// baseline (237.610 us; speedup 1.0000x reference)
//
#include <hip/hip_runtime.h>

// IF (integrate-and-fire) forward, T=4.
// Per position: mem = 0.5*th; for t: mem += x_t; s = (mem>=th)?th:0; out_t = s; mem -= s.
// R7: DRAM-stream-count theory. R1-R6 all ran 2.2-2.5 TB/s regardless of
// pipelining depth (in-flight theory falsified: 64KB/CU in flight vs 9KB
// needed). Known-good fill/copy kernels (6.3-6.7 TB/s) have 1-2 dense streams
// per block; we had 8 streams x 2048 resident blocks = ~16K concurrent DRAM
// streams (~125/channel -> row thrash). Fix: 256 blocks x 512 threads, each
// block walks a contiguous chunk sequentially -> 2048 streams (~16/channel),
// each strictly sequential. TLP (16 waves/CU) covers latency.

typedef float f32x4 __attribute__((ext_vector_type(4)));

__global__ __launch_bounds__(512) void if_fwd_kernel(
    const f32x4* __restrict__ x,
    const float* __restrict__ thresh_p,
    f32x4* __restrict__ out,
    int n4,     // f32x4 positions per timestep
    int chunk)  // f32x4 positions per block (contiguous)
{
    const float th = thresh_p[0];
    const float m0 = 0.5f * th;

    const int begin = blockIdx.x * chunk;
    const int end   = begin + chunk;

    // Each iteration: the block's 16 waves read a contiguous 8KB span of each
    // of the 4 timestep streams, then advance. 4 read + 4 write streams per
    // block, all strictly sequential -> DRAM row hits.
    for (int i = begin + threadIdx.x; i < end; i += 512) {
        f32x4 v0 = x[0 * n4 + i];
        f32x4 v1 = x[1 * n4 + i];
        f32x4 v2 = x[2 * n4 + i];
        f32x4 v3 = x[3 * n4 + i];

        f32x4 m = m0;
        f32x4 s;

        m += v0;
        s.x = (m.x >= th) ? th : 0.0f;
        s.y = (m.y >= th) ? th : 0.0f;
        s.z = (m.z >= th) ? th : 0.0f;
        s.w = (m.w >= th) ? th : 0.0f;
        out[0 * n4 + i] = s;
        m -= s;

        m += v1;
        s.x = (m.x >= th) ? th : 0.0f;
        s.y = (m.y >= th) ? th : 0.0f;
        s.z = (m.z >= th) ? th : 0.0f;
        s.w = (m.w >= th) ? th : 0.0f;
        out[1 * n4 + i] = s;
        m -= s;

        m += v2;
        s.x = (m.x >= th) ? th : 0.0f;
        s.y = (m.y >= th) ? th : 0.0f;
        s.z = (m.z >= th) ? th : 0.0f;
        s.w = (m.w >= th) ? th : 0.0f;
        out[2 * n4 + i] = s;
        m -= s;

        m += v3;
        s.x = (m.x >= th) ? th : 0.0f;
        s.y = (m.y >= th) ? th : 0.0f;
        s.z = (m.z >= th) ? th : 0.0f;
        s.w = (m.w >= th) ? th : 0.0f;
        out[3 * n4 + i] = s;
        // final mem discarded
    }
}

extern "C" void kernel_launch(void* const* d_in, const int* in_sizes, int n_in,
                              void* d_out, int out_size, void* d_ws, size_t ws_size,
                              hipStream_t stream) {
    const float* x      = (const float*)d_in[0];
    const float* thresh = (const float*)d_in[1];
    float* out          = (float*)d_out;

    const int total   = in_sizes[0];   // 33,554,432 = T*B*C*H*W (T=4)
    const int n_per_t = total / 4;     // 8,388,608
    const int n4      = n_per_t / 4;   // 2,097,152 f32x4 per timestep

    const int block = 512;
    const int grid  = 256;                 // 1 block per CU
    const int chunk = n4 / grid;           // 8192 f32x4 per block per timestep

    if_fwd_kernel<<<grid, block, 0, stream>>>(
        (const f32x4*)x, thresh, (f32x4*)out, n4, chunk);
}